// Round 6
// baseline (220.915 us; speedup 1.0000x reference)
//
#include <hip/hip_runtime.h>

// ---------------------------------------------------------------------------
// res_rand_GAE round 6: fused setup kernel (6 launches -> 1), 2-phase
// reg-staged pipeline in the MFMA GEMMs, unroll-8 CSR gather.
// Outputs: x [N,128] ++ A [N,1] fp32 in d_out.
// ---------------------------------------------------------------------------

typedef unsigned short u16;
typedef short bf16x8 __attribute__((ext_vector_type(8)));
typedef unsigned short us8 __attribute__((ext_vector_type(8)));
typedef float f32x4 __attribute__((ext_vector_type(4)));

static inline int cdiv_ll(long long a, long long b) { return (int)((a + b - 1) / b); }

__device__ inline float bf2f(u16 u) {
    union { unsigned int i; float f; } v; v.i = ((unsigned int)u) << 16; return v.f;
}
__device__ inline u16 f2bf(float x) {   // round-to-nearest-even
    union { float f; unsigned int i; } v; v.f = x;
    unsigned int r = v.i + 0x7fffu + ((v.i >> 16) & 1u);
    return (u16)(r >> 16);
}

// ---- fused setup: cnt=0, Aout=bfc2, emb->bf16, W1^T, Wcat^T, Wfc1^T --------

__global__ __launch_bounds__(256) void setup_kernel(const float* __restrict__ emb,
                                                    const float* __restrict__ W1,
                                                    const float* __restrict__ W2,
                                                    const float* __restrict__ Wres,
                                                    const float* __restrict__ Wfc1,
                                                    const float* __restrict__ bfc2,
                                                    u16* __restrict__ embb,
                                                    u16* __restrict__ W1t,
                                                    u16* __restrict__ Wct,
                                                    u16* __restrict__ Wfc1t,
                                                    int* __restrict__ cnt,
                                                    float* __restrict__ Aout,
                                                    int N) {
    long long r = (long long)blockIdx.x * 256 + threadIdx.x;
    const long long nf2b = (long long)N * 32;          // float4s of emb
    if (r < nf2b) {
        float4 v = ((const float4*)emb)[r];
        uint2 o;
        o.x = (unsigned)f2bf(v.x) | ((unsigned)f2bf(v.y) << 16);
        o.y = (unsigned)f2bf(v.z) | ((unsigned)f2bf(v.w) << 16);
        ((uint2*)embb)[r] = o;
        return;
    }
    r -= nf2b;
    if (r < 512 * 128) {                               // W1t[n*128+k] = W1[k*512+n]
        int n = (int)(r / 128), k = (int)(r % 128);
        W1t[r] = f2bf(W1[(size_t)k * 512 + n]);
        return;
    }
    r -= 512 * 128;
    if (r < 256 * 512) {                               // Wct[n*512+k]
        int n = (int)(r / 512), k = (int)(r % 512);
        float v = (n < 128) ? W2[(size_t)k * 128 + n] : Wres[(size_t)k * 128 + (n - 128)];
        Wct[r] = f2bf(v);
        return;
    }
    r -= 256 * 512;
    if (r < 256 * 128) {                               // Wfc1t[n*128+k]
        int n = (int)(r / 128), k = (int)(r % 128);
        Wfc1t[r] = f2bf(Wfc1[(size_t)k * 256 + n]);
        return;
    }
    r -= 256 * 128;
    if (r < N) { cnt[(int)r] = 0; return; }
    r -= N;
    if (r < N) Aout[(int)r] = bfc2[0];
}

// ---- CSR build -------------------------------------------------------------

__global__ __launch_bounds__(256) void hist_kernel(const int* __restrict__ dst,
                                                   int* __restrict__ cnt, int E) {
    int e = blockIdx.x * 256 + threadIdx.x;
    if (e < E) atomicAdd(&cnt[dst[e]], 1);
}

__global__ __launch_bounds__(256) void scanA_kernel(const int* __restrict__ cnt,
                                                    int* __restrict__ excl,
                                                    int* __restrict__ bsum, int N) {
    __shared__ int tmp[256];
    int i = blockIdx.x * 256 + threadIdx.x;
    int v = (i < N) ? cnt[i] : 0;
    tmp[threadIdx.x] = v;
    __syncthreads();
    for (int o = 1; o < 256; o <<= 1) {
        int t = (threadIdx.x >= (unsigned)o) ? tmp[threadIdx.x - o] : 0;
        __syncthreads();
        tmp[threadIdx.x] += t;
        __syncthreads();
    }
    if (i < N) excl[i] = tmp[threadIdx.x] - v;
    if (threadIdx.x == 255) bsum[blockIdx.x] = tmp[255];
}

__global__ __launch_bounds__(256) void scanB_kernel(int* __restrict__ bsum, int nb) {
    __shared__ int tmp[256];
    int v = (threadIdx.x < (unsigned)nb) ? bsum[threadIdx.x] : 0;
    tmp[threadIdx.x] = v;
    __syncthreads();
    for (int o = 1; o < 256; o <<= 1) {
        int t = (threadIdx.x >= (unsigned)o) ? tmp[threadIdx.x - o] : 0;
        __syncthreads();
        tmp[threadIdx.x] += t;
        __syncthreads();
    }
    if (threadIdx.x < (unsigned)nb) bsum[threadIdx.x] = tmp[threadIdx.x] - v;
}

__global__ __launch_bounds__(256) void scanC_kernel(const int* __restrict__ excl,
                                                    const int* __restrict__ bsum,
                                                    const int* __restrict__ cnt,
                                                    int* __restrict__ rowptr,
                                                    int* __restrict__ cursor,
                                                    float* __restrict__ dinv,
                                                    int N, int E) {
    int i = blockIdx.x * 256 + threadIdx.x;
    if (i < N) {
        int r = excl[i] + bsum[blockIdx.x];
        rowptr[i] = r;
        cursor[i] = r;
        dinv[i] = rsqrtf((float)cnt[i] + 2.0f);
    }
    if (i == 0) rowptr[N] = E;
}

__global__ __launch_bounds__(256) void fill_kernel(const int* __restrict__ src,
                                                   const int* __restrict__ dst,
                                                   const float* __restrict__ dinv,
                                                   int* __restrict__ cursor,
                                                   int* __restrict__ csr_src,
                                                   float* __restrict__ csr_w, int E) {
    int e = blockIdx.x * 256 + threadIdx.x;
    if (e >= E) return;
    int s = src[e], d = dst[e];
    int idx = atomicAdd(&cursor[d], 1);
    csr_src[idx] = s;
    csr_w[idx] = dinv[s] * dinv[d];
}

// ---- wave-per-node CSR aggregation over bf16 table [N][128] ----------------

#define AGG_EDGE(SR, WR)                                                       \
    {                                                                          \
        unsigned int vv = hp[(size_t)(SR) * 64 + lane];                        \
        ax = fmaf(bf2f((u16)vv), (WR), ax);                                    \
        ay = fmaf(bf2f((u16)(vv >> 16)), (WR), ay);                            \
    }

__device__ inline void agg_row(const unsigned int* __restrict__ hp,
                               const int* __restrict__ rowptr,
                               const int* __restrict__ csr_src,
                               const float* __restrict__ csr_w,
                               const float* __restrict__ dinv,
                               int wid, int lane, float& ax, float& ay) {
    float dv = dinv[wid];
    unsigned int hv = hp[(size_t)wid * 64 + lane];
    float c0 = 2.0f * dv * dv;
    ax = bf2f((u16)hv) * c0;
    ay = bf2f((u16)(hv >> 16)) * c0;
    int e = rowptr[wid], e1 = rowptr[wid + 1];
    for (; e + 7 < e1; e += 8) {
        int s0 = csr_src[e + 0], s1 = csr_src[e + 1], s2 = csr_src[e + 2], s3 = csr_src[e + 3];
        int s4 = csr_src[e + 4], s5 = csr_src[e + 5], s6 = csr_src[e + 6], s7 = csr_src[e + 7];
        float w0 = csr_w[e + 0], w1 = csr_w[e + 1], w2 = csr_w[e + 2], w3 = csr_w[e + 3];
        float w4 = csr_w[e + 4], w5 = csr_w[e + 5], w6 = csr_w[e + 6], w7 = csr_w[e + 7];
        AGG_EDGE(s0, w0); AGG_EDGE(s1, w1); AGG_EDGE(s2, w2); AGG_EDGE(s3, w3);
        AGG_EDGE(s4, w4); AGG_EDGE(s5, w5); AGG_EDGE(s6, w6); AGG_EDGE(s7, w7);
    }
    if (e + 3 < e1) {
        int s0 = csr_src[e + 0], s1 = csr_src[e + 1], s2 = csr_src[e + 2], s3 = csr_src[e + 3];
        float w0 = csr_w[e + 0], w1 = csr_w[e + 1], w2 = csr_w[e + 2], w3 = csr_w[e + 3];
        AGG_EDGE(s0, w0); AGG_EDGE(s1, w1); AGG_EDGE(s2, w2); AGG_EDGE(s3, w3);
        e += 4;
    }
    for (; e < e1; ++e) {
        int s0 = csr_src[e]; float w0 = csr_w[e];
        AGG_EDGE(s0, w0);
    }
}

__global__ __launch_bounds__(256) void aggb_kernel(const u16* __restrict__ hb,
                                                   const int* __restrict__ rowptr,
                                                   const int* __restrict__ csr_src,
                                                   const float* __restrict__ csr_w,
                                                   const float* __restrict__ dinv,
                                                   u16* __restrict__ out, int N) {
    int wid  = (blockIdx.x * blockDim.x + threadIdx.x) >> 6;
    int lane = threadIdx.x & 63;
    if (wid >= N) return;
    float ax, ay;
    agg_row((const unsigned int*)hb, rowptr, csr_src, csr_w, dinv, wid, lane, ax, ay);
    ((unsigned int*)out)[(size_t)wid * 64 + lane] =
        (unsigned)f2bf(ax) | ((unsigned)f2bf(ay) << 16);
}

// fused: x = relu(agg(h2) + b2) + hres + bres -> xout fp32 AND xb bf16
__global__ __launch_bounds__(256) void aggfin_kernel(const u16* __restrict__ hb,
                                                     const int* __restrict__ rowptr,
                                                     const int* __restrict__ csr_src,
                                                     const float* __restrict__ csr_w,
                                                     const float* __restrict__ dinv,
                                                     const float* __restrict__ b2,
                                                     const float* __restrict__ bres,
                                                     float* __restrict__ xout,
                                                     u16* __restrict__ xb, int N) {
    int wid  = (blockIdx.x * blockDim.x + threadIdx.x) >> 6;
    int lane = threadIdx.x & 63;
    if (wid >= N) return;
    float ax, ay;
    agg_row((const unsigned int*)hb, rowptr, csr_src, csr_w, dinv, wid, lane, ax, ay);
    float2 bb = ((const float2*)b2)[lane];
    float2 rr = ((const float2*)bres)[lane];
    float2 hres = ((float2*)xout)[(size_t)wid * 64 + lane];
    float ox = fmaxf(ax + bb.x, 0.f) + hres.x + rr.x;
    float oy = fmaxf(ay + bb.y, 0.f) + hres.y + rr.y;
    ((float2*)xout)[(size_t)wid * 64 + lane] = make_float2(ox, oy);
    ((unsigned int*)xb)[(size_t)wid * 64 + lane] =
        (unsigned)f2bf(ox) | ((unsigned)f2bf(oy) << 16);
}

// ---- bf16 MFMA GEMM: C = A[M][K] @ Bt[Nn][K]^T -----------------------------
// BM=128 BN=256 BK=64, 512 threads = 8 waves (2 row x 4 col), 16x16x32 MFMA.
// 2-phase reg-staged pipeline: next K-tile's global loads issue before the
// MFMA cluster so HBM latency hides under compute (T3-minimal).
// MODE 1: Cb = bf16(relu(C + bias))            [M][Nn]
// MODE 2: col<128 -> Cb bf16 [M][128]; col>=128 -> Cf f32 [M][128]
// MODE 3: Cf[row] += sum_col relu(C + bias[col]) * w2[col]   (atomic)

template <int MODE>
__global__ __launch_bounds__(512) void mgemm(const u16* __restrict__ A,
                                             const u16* __restrict__ Bt,
                                             int M, int Nn, int K,
                                             const float* __restrict__ bias,
                                             u16* __restrict__ Cb,
                                             float* __restrict__ Cf,
                                             const float* __restrict__ w2) {
    __shared__ u16 As[128][72];   // 18.4 KB (+8 pad, 16B-aligned rows)
    __shared__ u16 Bs[256][72];   // 36.9 KB
    const int t = threadIdx.x;
    const int bm = blockIdx.y * 128;
    const int bn = blockIdx.x * 256;
    const int w = t >> 6, lane = t & 63;
    const int wm = w >> 2, wn = w & 3;        // 2 x 4 wave grid
    const int l15 = lane & 15, lg = lane >> 4;
    const int srow = t >> 3, scol = (t & 7) * 8;   // staging: row += 64*i

    f32x4 acc[4][4];
#pragma unroll
    for (int i = 0; i < 4; ++i)
#pragma unroll
        for (int j = 0; j < 4; ++j) acc[i][j] = (f32x4)(0.0f);

    us8 ra[2], rb[4];
    // prologue: stage K-tile 0 into registers
#pragma unroll
    for (int i = 0; i < 2; ++i) {
        int row = srow + 64 * i;
        us8 v = (us8)(u16)0;
        if (bm + row < M) v = *(const us8*)(A + (size_t)(bm + row) * K + scol);
        ra[i] = v;
    }
#pragma unroll
    for (int i = 0; i < 4; ++i) {
        int row = srow + 64 * i;
        rb[i] = *(const us8*)(Bt + (size_t)(bn + row) * K + scol);
    }

    for (int kk = 0; kk < K; kk += 64) {
        // write staged regs -> LDS
#pragma unroll
        for (int i = 0; i < 2; ++i) *(us8*)&As[srow + 64 * i][scol] = ra[i];
#pragma unroll
        for (int i = 0; i < 4; ++i) *(us8*)&Bs[srow + 64 * i][scol] = rb[i];
        __syncthreads();

        // issue next tile's global loads (complete during the MFMA cluster)
        if (kk + 64 < K) {
#pragma unroll
            for (int i = 0; i < 2; ++i) {
                int row = srow + 64 * i;
                us8 v = (us8)(u16)0;
                if (bm + row < M)
                    v = *(const us8*)(A + (size_t)(bm + row) * K + kk + 64 + scol);
                ra[i] = v;
            }
#pragma unroll
            for (int i = 0; i < 4; ++i) {
                int row = srow + 64 * i;
                rb[i] = *(const us8*)(Bt + (size_t)(bn + row) * K + kk + 64 + scol);
            }
        }

#pragma unroll
        for (int ks = 0; ks < 2; ++ks) {
            const int ko = 32 * ks + lg * 8;
            bf16x8 bfr[4], afr[4];
#pragma unroll
            for (int fn = 0; fn < 4; ++fn)
                bfr[fn] = *(const bf16x8*)&Bs[64 * wn + 16 * fn + l15][ko];
#pragma unroll
            for (int fm = 0; fm < 4; ++fm)
                afr[fm] = *(const bf16x8*)&As[64 * wm + 16 * fm + l15][ko];
#pragma unroll
            for (int fm = 0; fm < 4; ++fm)
#pragma unroll
                for (int fn = 0; fn < 4; ++fn)
                    acc[fm][fn] = __builtin_amdgcn_mfma_f32_16x16x32_bf16(
                        afr[fm], bfr[fn], acc[fm][fn], 0, 0, 0);
        }
        __syncthreads();
    }

    if (MODE == 3) {
        float bl[4], wl[4];
#pragma unroll
        for (int fn = 0; fn < 4; ++fn) {
            int col = bn + 64 * wn + 16 * fn + l15;
            bl[fn] = bias[col];
            wl[fn] = w2[col];
        }
#pragma unroll
        for (int fm = 0; fm < 4; ++fm) {
#pragma unroll
            for (int r = 0; r < 4; ++r) {
                int row = bm + 64 * wm + 16 * fm + lg * 4 + r;
                float p = 0.f;
#pragma unroll
                for (int fn = 0; fn < 4; ++fn)
                    p += fmaxf(acc[fm][fn][r] + bl[fn], 0.f) * wl[fn];
                p += __shfl_xor(p, 1);
                p += __shfl_xor(p, 2);
                p += __shfl_xor(p, 4);
                p += __shfl_xor(p, 8);
                if (l15 == 0 && row < M) atomicAdd(&Cf[row], p);
            }
        }
        return;
    }

#pragma unroll
    for (int fm = 0; fm < 4; ++fm) {
#pragma unroll
        for (int fn = 0; fn < 4; ++fn) {
            const int col = bn + 64 * wn + 16 * fn + l15;
#pragma unroll
            for (int r = 0; r < 4; ++r) {
                int row = bm + 64 * wm + 16 * fm + lg * 4 + r;
                if (row < M) {
                    float v = acc[fm][fn][r];
                    if (MODE == 1) {
                        v = fmaxf(v + bias[col], 0.0f);
                        Cb[(size_t)row * Nn + col] = f2bf(v);
                    } else {
                        if (col < 128) Cb[(size_t)row * 128 + col] = f2bf(v);
                        else           Cf[(size_t)row * 128 + (col - 128)] = v;
                    }
                }
            }
        }
    }
}

// ---------------------------------------------------------------------------

extern "C" void kernel_launch(void* const* d_in, const int* in_sizes, int n_in,
                              void* d_out, int out_size, void* d_ws, size_t ws_size,
                              hipStream_t stream) {
    const float* emb  = (const float*)d_in[0];
    const int*   eidx = (const int*)d_in[1];
    const float* W1   = (const float*)d_in[2];
    const float* b1   = (const float*)d_in[3];
    const float* W2   = (const float*)d_in[4];
    const float* b2   = (const float*)d_in[5];
    const float* Wres = (const float*)d_in[6];
    const float* bres = (const float*)d_in[7];
    const float* Wfc1 = (const float*)d_in[8];
    const float* bfc1 = (const float*)d_in[9];
    const float* Wfc2 = (const float*)d_in[10];
    const float* bfc2 = (const float*)d_in[11];

    const int N = in_sizes[0] / 128;
    const int E = in_sizes[1] / 2;
    const int* srcv = eidx;
    const int* dstv = eidx + E;

    float* out  = (float*)d_out;
    float* xout = out;                       // [N,128]
    float* Aout = out + (size_t)N * 128;     // [N]

    // ---- workspace layout ----
    char* p = (char*)d_ws;
    float* dinv  = (float*)p;            p += (size_t)N * 4;
    float* csr_w = (float*)p;            p += (size_t)E * 4;
    u16*  embb   = (u16*)p;              p += (size_t)N * 128 * 2;
    u16*  aggEb  = (u16*)p;              p += (size_t)N * 128 * 2;
    u16*  x1b    = (u16*)p;              p += (size_t)N * 512 * 2;
    u16*  h2b    = (u16*)p;              p += (size_t)N * 128 * 2;
    u16*  xb     = (u16*)p;              p += (size_t)N * 128 * 2;
    u16*  W1t    = (u16*)p;              p += (size_t)512 * 128 * 2;
    u16*  Wct    = (u16*)p;              p += (size_t)256 * 512 * 2;
    u16*  Wfc1t  = (u16*)p;              p += (size_t)256 * 128 * 2;
    int*  cnt     = (int*)p;             p += (size_t)N * 4;
    int*  excl    = (int*)p;             p += (size_t)N * 4;
    int*  rowptr  = (int*)p;             p += (size_t)(N + 1) * 4;
    int*  cursor  = (int*)p;             p += (size_t)N * 4;
    int*  bsum    = (int*)p;             p += 256 * 4;
    int*  csr_src = (int*)p;             p += (size_t)E * 4;

    const int T  = 256;
    const int nb = cdiv_ll(N, 256);      // <= 256 required by scanB

    // 1) fused setup (also zeroes cnt, inits Aout=bfc2)
    const long long setup_work = (long long)N * 32 + 512 * 128 + 256 * 512
                               + 256 * 128 + (long long)N + (long long)N;
    setup_kernel<<<cdiv_ll(setup_work, T), T, 0, stream>>>(
        emb, W1, W2, Wres, Wfc1, bfc2, embb, W1t, Wct, Wfc1t, cnt, Aout, N);

    // 2) CSR build + dinv (stream order guarantees cnt=0 before hist)
    hist_kernel<<<cdiv_ll(E, T), T, 0, stream>>>(dstv, cnt, E);
    scanA_kernel<<<nb, T, 0, stream>>>(cnt, excl, bsum, N);
    scanB_kernel<<<1, T, 0, stream>>>(bsum, nb);
    scanC_kernel<<<nb, T, 0, stream>>>(excl, bsum, cnt, rowptr, cursor, dinv, N, E);
    fill_kernel<<<cdiv_ll(E, T), T, 0, stream>>>(srcv, dstv, dinv, cursor, csr_src, csr_w, E);

    // 3) aggE = S @ emb  (bf16)
    aggb_kernel<<<cdiv_ll((long long)N * 64, T), T, 0, stream>>>(
        embb, rowptr, csr_src, csr_w, dinv, aggEb, N);

    // 4) x1 = relu(aggE @ W1 + b1) -> bf16 [N,512]
    mgemm<1><<<dim3(512 / 256, cdiv_ll(N, 128)), 512, 0, stream>>>(
        aggEb, W1t, N, 512, 128, b1, x1b, nullptr, nullptr);

    // 5) fused: h2 = x1@W2 (bf16), hres = x1@Wres (fp32 -> xout)
    mgemm<2><<<dim3(1, cdiv_ll(N, 128)), 512, 0, stream>>>(
        x1b, Wct, N, 256, 512, nullptr, h2b, xout, nullptr);

    // 6) fused: x = relu(S@h2 + b2) + hres + bres -> xout (fp32) + xb (bf16)
    aggfin_kernel<<<cdiv_ll((long long)N * 64, T), T, 0, stream>>>(
        h2b, rowptr, csr_src, csr_w, dinv, b2, bres, xout, xb, N);

    // 7) head: A += sum relu(xb@Wfc1t + bfc1) * Wfc2  (A pre-init to bfc2)
    mgemm<3><<<dim3(1, cdiv_ll(N, 128)), 512, 0, stream>>>(
        xb, Wfc1t, N, 256, 128, bfc1, nullptr, Aout, Wfc2);
}

// Round 7
// 197.975 us; speedup vs baseline: 1.1159x; 1.1159x over previous
//
#include <hip/hip_runtime.h>

// ---------------------------------------------------------------------------
// res_rand_GAE round 7: swapped-operand MFMA (lane holds 4 consecutive output
// cols -> packed 8B/16B stores, 4x fewer store instrs), reg-staging pipeline
// only where K is deep (MODE2, K=512). Outputs: x [N,128] ++ A [N,1] fp32.
// ---------------------------------------------------------------------------

typedef unsigned short u16;
typedef short bf16x8 __attribute__((ext_vector_type(8)));
typedef unsigned short us8 __attribute__((ext_vector_type(8)));
typedef float f32x4 __attribute__((ext_vector_type(4)));

static inline int cdiv_ll(long long a, long long b) { return (int)((a + b - 1) / b); }

__device__ inline float bf2f(u16 u) {
    union { unsigned int i; float f; } v; v.i = ((unsigned int)u) << 16; return v.f;
}
__device__ inline u16 f2bf(float x) {   // round-to-nearest-even
    union { float f; unsigned int i; } v; v.f = x;
    unsigned int r = v.i + 0x7fffu + ((v.i >> 16) & 1u);
    return (u16)(r >> 16);
}

// ---- fused setup: cnt=0, Aout=bfc2, emb->bf16, W1^T, Wcat^T, Wfc1^T --------

__global__ __launch_bounds__(256) void setup_kernel(const float* __restrict__ emb,
                                                    const float* __restrict__ W1,
                                                    const float* __restrict__ W2,
                                                    const float* __restrict__ Wres,
                                                    const float* __restrict__ Wfc1,
                                                    const float* __restrict__ bfc2,
                                                    u16* __restrict__ embb,
                                                    u16* __restrict__ W1t,
                                                    u16* __restrict__ Wct,
                                                    u16* __restrict__ Wfc1t,
                                                    int* __restrict__ cnt,
                                                    float* __restrict__ Aout,
                                                    int N) {
    long long r = (long long)blockIdx.x * 256 + threadIdx.x;
    const long long nf2b = (long long)N * 32;          // float4s of emb
    if (r < nf2b) {
        float4 v = ((const float4*)emb)[r];
        uint2 o;
        o.x = (unsigned)f2bf(v.x) | ((unsigned)f2bf(v.y) << 16);
        o.y = (unsigned)f2bf(v.z) | ((unsigned)f2bf(v.w) << 16);
        ((uint2*)embb)[r] = o;
        return;
    }
    r -= nf2b;
    if (r < 512 * 128) {                               // W1t[n*128+k] = W1[k*512+n]
        int n = (int)(r / 128), k = (int)(r % 128);
        W1t[r] = f2bf(W1[(size_t)k * 512 + n]);
        return;
    }
    r -= 512 * 128;
    if (r < 256 * 512) {                               // Wct[n*512+k]
        int n = (int)(r / 512), k = (int)(r % 512);
        float v = (n < 128) ? W2[(size_t)k * 128 + n] : Wres[(size_t)k * 128 + (n - 128)];
        Wct[r] = f2bf(v);
        return;
    }
    r -= 256 * 512;
    if (r < 256 * 128) {                               // Wfc1t[n*128+k]
        int n = (int)(r / 128), k = (int)(r % 128);
        Wfc1t[r] = f2bf(Wfc1[(size_t)k * 256 + n]);
        return;
    }
    r -= 256 * 128;
    if (r < N) { cnt[(int)r] = 0; return; }
    r -= N;
    if (r < N) Aout[(int)r] = bfc2[0];
}

// ---- CSR build -------------------------------------------------------------

__global__ __launch_bounds__(256) void hist_kernel(const int* __restrict__ dst,
                                                   int* __restrict__ cnt, int E) {
    int e = blockIdx.x * 256 + threadIdx.x;
    if (e < E) atomicAdd(&cnt[dst[e]], 1);
}

__global__ __launch_bounds__(256) void scanA_kernel(const int* __restrict__ cnt,
                                                    int* __restrict__ excl,
                                                    int* __restrict__ bsum, int N) {
    __shared__ int tmp[256];
    int i = blockIdx.x * 256 + threadIdx.x;
    int v = (i < N) ? cnt[i] : 0;
    tmp[threadIdx.x] = v;
    __syncthreads();
    for (int o = 1; o < 256; o <<= 1) {
        int t = (threadIdx.x >= (unsigned)o) ? tmp[threadIdx.x - o] : 0;
        __syncthreads();
        tmp[threadIdx.x] += t;
        __syncthreads();
    }
    if (i < N) excl[i] = tmp[threadIdx.x] - v;
    if (threadIdx.x == 255) bsum[blockIdx.x] = tmp[255];
}

__global__ __launch_bounds__(256) void scanB_kernel(int* __restrict__ bsum, int nb) {
    __shared__ int tmp[256];
    int v = (threadIdx.x < (unsigned)nb) ? bsum[threadIdx.x] : 0;
    tmp[threadIdx.x] = v;
    __syncthreads();
    for (int o = 1; o < 256; o <<= 1) {
        int t = (threadIdx.x >= (unsigned)o) ? tmp[threadIdx.x - o] : 0;
        __syncthreads();
        tmp[threadIdx.x] += t;
        __syncthreads();
    }
    if (threadIdx.x < (unsigned)nb) bsum[threadIdx.x] = tmp[threadIdx.x] - v;
}

__global__ __launch_bounds__(256) void scanC_kernel(const int* __restrict__ excl,
                                                    const int* __restrict__ bsum,
                                                    const int* __restrict__ cnt,
                                                    int* __restrict__ rowptr,
                                                    int* __restrict__ cursor,
                                                    float* __restrict__ dinv,
                                                    int N, int E) {
    int i = blockIdx.x * 256 + threadIdx.x;
    if (i < N) {
        int r = excl[i] + bsum[blockIdx.x];
        rowptr[i] = r;
        cursor[i] = r;
        dinv[i] = rsqrtf((float)cnt[i] + 2.0f);
    }
    if (i == 0) rowptr[N] = E;
}

__global__ __launch_bounds__(256) void fill_kernel(const int* __restrict__ src,
                                                   const int* __restrict__ dst,
                                                   const float* __restrict__ dinv,
                                                   int* __restrict__ cursor,
                                                   int* __restrict__ csr_src,
                                                   float* __restrict__ csr_w, int E) {
    int e = blockIdx.x * 256 + threadIdx.x;
    if (e >= E) return;
    int s = src[e], d = dst[e];
    int idx = atomicAdd(&cursor[d], 1);
    csr_src[idx] = s;
    csr_w[idx] = dinv[s] * dinv[d];
}

// ---- wave-per-node CSR aggregation over bf16 table [N][128] ----------------

#define AGG_EDGE(SR, WR)                                                       \
    {                                                                          \
        unsigned int vv = hp[(size_t)(SR) * 64 + lane];                        \
        ax = fmaf(bf2f((u16)vv), (WR), ax);                                    \
        ay = fmaf(bf2f((u16)(vv >> 16)), (WR), ay);                            \
    }

__device__ inline void agg_row(const unsigned int* __restrict__ hp,
                               const int* __restrict__ rowptr,
                               const int* __restrict__ csr_src,
                               const float* __restrict__ csr_w,
                               const float* __restrict__ dinv,
                               int wid, int lane, float& ax, float& ay) {
    float dv = dinv[wid];
    unsigned int hv = hp[(size_t)wid * 64 + lane];
    float c0 = 2.0f * dv * dv;
    ax = bf2f((u16)hv) * c0;
    ay = bf2f((u16)(hv >> 16)) * c0;
    int e = rowptr[wid], e1 = rowptr[wid + 1];
    for (; e + 7 < e1; e += 8) {
        int s0 = csr_src[e + 0], s1 = csr_src[e + 1], s2 = csr_src[e + 2], s3 = csr_src[e + 3];
        int s4 = csr_src[e + 4], s5 = csr_src[e + 5], s6 = csr_src[e + 6], s7 = csr_src[e + 7];
        float w0 = csr_w[e + 0], w1 = csr_w[e + 1], w2 = csr_w[e + 2], w3 = csr_w[e + 3];
        float w4 = csr_w[e + 4], w5 = csr_w[e + 5], w6 = csr_w[e + 6], w7 = csr_w[e + 7];
        AGG_EDGE(s0, w0); AGG_EDGE(s1, w1); AGG_EDGE(s2, w2); AGG_EDGE(s3, w3);
        AGG_EDGE(s4, w4); AGG_EDGE(s5, w5); AGG_EDGE(s6, w6); AGG_EDGE(s7, w7);
    }
    if (e + 3 < e1) {
        int s0 = csr_src[e + 0], s1 = csr_src[e + 1], s2 = csr_src[e + 2], s3 = csr_src[e + 3];
        float w0 = csr_w[e + 0], w1 = csr_w[e + 1], w2 = csr_w[e + 2], w3 = csr_w[e + 3];
        AGG_EDGE(s0, w0); AGG_EDGE(s1, w1); AGG_EDGE(s2, w2); AGG_EDGE(s3, w3);
        e += 4;
    }
    for (; e < e1; ++e) {
        int s0 = csr_src[e]; float w0 = csr_w[e];
        AGG_EDGE(s0, w0);
    }
}

__global__ __launch_bounds__(256) void aggb_kernel(const u16* __restrict__ hb,
                                                   const int* __restrict__ rowptr,
                                                   const int* __restrict__ csr_src,
                                                   const float* __restrict__ csr_w,
                                                   const float* __restrict__ dinv,
                                                   u16* __restrict__ out, int N) {
    int wid  = (blockIdx.x * blockDim.x + threadIdx.x) >> 6;
    int lane = threadIdx.x & 63;
    if (wid >= N) return;
    float ax, ay;
    agg_row((const unsigned int*)hb, rowptr, csr_src, csr_w, dinv, wid, lane, ax, ay);
    ((unsigned int*)out)[(size_t)wid * 64 + lane] =
        (unsigned)f2bf(ax) | ((unsigned)f2bf(ay) << 16);
}

// fused: x = relu(agg(h2) + b2) + hres + bres -> xout fp32 AND xb bf16
__global__ __launch_bounds__(256) void aggfin_kernel(const u16* __restrict__ hb,
                                                     const int* __restrict__ rowptr,
                                                     const int* __restrict__ csr_src,
                                                     const float* __restrict__ csr_w,
                                                     const float* __restrict__ dinv,
                                                     const float* __restrict__ b2,
                                                     const float* __restrict__ bres,
                                                     float* __restrict__ xout,
                                                     u16* __restrict__ xb, int N) {
    int wid  = (blockIdx.x * blockDim.x + threadIdx.x) >> 6;
    int lane = threadIdx.x & 63;
    if (wid >= N) return;
    float ax, ay;
    agg_row((const unsigned int*)hb, rowptr, csr_src, csr_w, dinv, wid, lane, ax, ay);
    float2 bb = ((const float2*)b2)[lane];
    float2 rr = ((const float2*)bres)[lane];
    float2 hres = ((float2*)xout)[(size_t)wid * 64 + lane];
    float ox = fmaxf(ax + bb.x, 0.f) + hres.x + rr.x;
    float oy = fmaxf(ay + bb.y, 0.f) + hres.y + rr.y;
    ((float2*)xout)[(size_t)wid * 64 + lane] = make_float2(ox, oy);
    ((unsigned int*)xb)[(size_t)wid * 64 + lane] =
        (unsigned)f2bf(ox) | ((unsigned)f2bf(oy) << 16);
}

// ---- bf16 MFMA GEMM: C = A[M][K] @ Bt[Nn][K]^T -----------------------------
// BM=128 BN=256 BK=64, 512 threads = 8 waves (2 row x 4 col), 16x16x32 MFMA.
// SWAPPED operands: acc = mfma(bfr, afr, acc) so D has m = lane&15 and
// n = 4*lg + reg -> each lane owns 4 consecutive output columns (packed
// 8B/16B stores). PIPE=1 adds 2-phase reg-staged prefetch (only pays for
// deep K). MODE 1: Cb = bf16(relu(C+bias)); MODE 2: col<128 -> Cb bf16,
// col>=128 -> Cf f32; MODE 3: Cf[row] += sum_col relu(C+bias)*w2 (atomic).

template <int MODE, int PIPE>
__global__ __launch_bounds__(512) void mgemm(const u16* __restrict__ A,
                                             const u16* __restrict__ Bt,
                                             int M, int Nn, int K,
                                             const float* __restrict__ bias,
                                             u16* __restrict__ Cb,
                                             float* __restrict__ Cf,
                                             const float* __restrict__ w2) {
    __shared__ u16 As[128][72];   // 18.4 KB (+8 pad, 16B-aligned rows)
    __shared__ u16 Bs[256][72];   // 36.9 KB
    const int t = threadIdx.x;
    const int bm = blockIdx.y * 128;
    const int bn = blockIdx.x * 256;
    const int w = t >> 6, lane = t & 63;
    const int wm = w >> 2, wn = w & 3;        // 2 x 4 wave grid
    const int l15 = lane & 15, lg = lane >> 4;
    const int srow = t >> 3, scol = (t & 7) * 8;   // staging: row += 64*i

    f32x4 acc[4][4];
#pragma unroll
    for (int i = 0; i < 4; ++i)
#pragma unroll
        for (int j = 0; j < 4; ++j) acc[i][j] = (f32x4)(0.0f);

    us8 ra[2], rb[4];
    if (PIPE) {   // prologue: stage K-tile 0 into registers
#pragma unroll
        for (int i = 0; i < 2; ++i) {
            int row = srow + 64 * i;
            us8 v = (us8)(u16)0;
            if (bm + row < M) v = *(const us8*)(A + (size_t)(bm + row) * K + scol);
            ra[i] = v;
        }
#pragma unroll
        for (int i = 0; i < 4; ++i)
            rb[i] = *(const us8*)(Bt + (size_t)(bn + srow + 64 * i) * K + scol);
    }

    for (int kk = 0; kk < K; kk += 64) {
        if (PIPE) {
#pragma unroll
            for (int i = 0; i < 2; ++i) *(us8*)&As[srow + 64 * i][scol] = ra[i];
#pragma unroll
            for (int i = 0; i < 4; ++i) *(us8*)&Bs[srow + 64 * i][scol] = rb[i];
        } else {
#pragma unroll
            for (int i = 0; i < 2; ++i) {
                int row = srow + 64 * i;
                us8 v = (us8)(u16)0;
                if (bm + row < M)
                    v = *(const us8*)(A + (size_t)(bm + row) * K + kk + scol);
                *(us8*)&As[row][scol] = v;
            }
#pragma unroll
            for (int i = 0; i < 4; ++i) {
                int row = srow + 64 * i;
                *(us8*)&Bs[row][scol] =
                    *(const us8*)(Bt + (size_t)(bn + row) * K + kk + scol);
            }
        }
        __syncthreads();

        if (PIPE && kk + 64 < K) {   // issue next tile's loads under the MFMAs
#pragma unroll
            for (int i = 0; i < 2; ++i) {
                int row = srow + 64 * i;
                us8 v = (us8)(u16)0;
                if (bm + row < M)
                    v = *(const us8*)(A + (size_t)(bm + row) * K + kk + 64 + scol);
                ra[i] = v;
            }
#pragma unroll
            for (int i = 0; i < 4; ++i)
                rb[i] = *(const us8*)(Bt + (size_t)(bn + srow + 64 * i) * K + kk + 64 + scol);
        }

#pragma unroll
        for (int ks = 0; ks < 2; ++ks) {
            const int ko = 32 * ks + lg * 8;
            bf16x8 bfr[4], afr[4];
#pragma unroll
            for (int fn = 0; fn < 4; ++fn)
                bfr[fn] = *(const bf16x8*)&Bs[64 * wn + 16 * fn + l15][ko];
#pragma unroll
            for (int fm = 0; fm < 4; ++fm)
                afr[fm] = *(const bf16x8*)&As[64 * wm + 16 * fm + l15][ko];
#pragma unroll
            for (int fm = 0; fm < 4; ++fm)
#pragma unroll
                for (int fn = 0; fn < 4; ++fn)
                    acc[fm][fn] = __builtin_amdgcn_mfma_f32_16x16x32_bf16(
                        bfr[fn], afr[fm], acc[fm][fn], 0, 0, 0);   // SWAPPED
        }
        __syncthreads();
    }

    // epilogue: lane owns rows m = bm+64*wm+16*fm+l15, cols n0 = bn+64*wn+16*fn+4*lg
    if (MODE == 3) {
        float4 bl4[4], wl4[4];
#pragma unroll
        for (int fn = 0; fn < 4; ++fn) {
            int c = bn + 64 * wn + 16 * fn + 4 * lg;
            bl4[fn] = *(const float4*)&bias[c];
            wl4[fn] = *(const float4*)&w2[c];
        }
#pragma unroll
        for (int fm = 0; fm < 4; ++fm) {
            float p = 0.f;
#pragma unroll
            for (int fn = 0; fn < 4; ++fn) {
                p += fmaxf(acc[fm][fn][0] + bl4[fn].x, 0.f) * wl4[fn].x;
                p += fmaxf(acc[fm][fn][1] + bl4[fn].y, 0.f) * wl4[fn].y;
                p += fmaxf(acc[fm][fn][2] + bl4[fn].z, 0.f) * wl4[fn].z;
                p += fmaxf(acc[fm][fn][3] + bl4[fn].w, 0.f) * wl4[fn].w;
            }
            p += __shfl_xor(p, 16);
            p += __shfl_xor(p, 32);
            int row = bm + 64 * wm + 16 * fm + l15;
            if (lane < 16 && row < M) atomicAdd(&Cf[row], p);
        }
        return;
    }

#pragma unroll
    for (int fm = 0; fm < 4; ++fm) {
        const int row = bm + 64 * wm + 16 * fm + l15;
        if (row >= M) continue;
#pragma unroll
        for (int fn = 0; fn < 4; ++fn) {
            const int col = bn + 64 * wn + 16 * fn + 4 * lg;
            f32x4 v = acc[fm][fn];
            if (MODE == 1) {
                float4 b4 = *(const float4*)&bias[col];
                float v0 = fmaxf(v[0] + b4.x, 0.f), v1 = fmaxf(v[1] + b4.y, 0.f);
                float v2 = fmaxf(v[2] + b4.z, 0.f), v3 = fmaxf(v[3] + b4.w, 0.f);
                uint2 o;
                o.x = (unsigned)f2bf(v0) | ((unsigned)f2bf(v1) << 16);
                o.y = (unsigned)f2bf(v2) | ((unsigned)f2bf(v3) << 16);
                *(uint2*)(Cb + (size_t)row * Nn + col) = o;
            } else {             // MODE 2
                if (col < 128) {
                    uint2 o;
                    o.x = (unsigned)f2bf(v[0]) | ((unsigned)f2bf(v[1]) << 16);
                    o.y = (unsigned)f2bf(v[2]) | ((unsigned)f2bf(v[3]) << 16);
                    *(uint2*)(Cb + (size_t)row * 128 + col) = o;
                } else {
                    *(float4*)(Cf + (size_t)row * 128 + (col - 128)) =
                        make_float4(v[0], v[1], v[2], v[3]);
                }
            }
        }
    }
}

// ---------------------------------------------------------------------------

extern "C" void kernel_launch(void* const* d_in, const int* in_sizes, int n_in,
                              void* d_out, int out_size, void* d_ws, size_t ws_size,
                              hipStream_t stream) {
    const float* emb  = (const float*)d_in[0];
    const int*   eidx = (const int*)d_in[1];
    const float* W1   = (const float*)d_in[2];
    const float* b1   = (const float*)d_in[3];
    const float* W2   = (const float*)d_in[4];
    const float* b2   = (const float*)d_in[5];
    const float* Wres = (const float*)d_in[6];
    const float* bres = (const float*)d_in[7];
    const float* Wfc1 = (const float*)d_in[8];
    const float* bfc1 = (const float*)d_in[9];
    const float* Wfc2 = (const float*)d_in[10];
    const float* bfc2 = (const float*)d_in[11];

    const int N = in_sizes[0] / 128;
    const int E = in_sizes[1] / 2;
    const int* srcv = eidx;
    const int* dstv = eidx + E;

    float* out  = (float*)d_out;
    float* xout = out;                       // [N,128]
    float* Aout = out + (size_t)N * 128;     // [N]

    // ---- workspace layout ----
    char* p = (char*)d_ws;
    float* dinv  = (float*)p;            p += (size_t)N * 4;
    float* csr_w = (float*)p;            p += (size_t)E * 4;
    u16*  embb   = (u16*)p;              p += (size_t)N * 128 * 2;
    u16*  aggEb  = (u16*)p;              p += (size_t)N * 128 * 2;
    u16*  x1b    = (u16*)p;              p += (size_t)N * 512 * 2;
    u16*  h2b    = (u16*)p;              p += (size_t)N * 128 * 2;
    u16*  xb     = (u16*)p;              p += (size_t)N * 128 * 2;
    u16*  W1t    = (u16*)p;              p += (size_t)512 * 128 * 2;
    u16*  Wct    = (u16*)p;              p += (size_t)256 * 512 * 2;
    u16*  Wfc1t  = (u16*)p;              p += (size_t)256 * 128 * 2;
    int*  cnt     = (int*)p;             p += (size_t)N * 4;
    int*  excl    = (int*)p;             p += (size_t)N * 4;
    int*  rowptr  = (int*)p;             p += (size_t)(N + 1) * 4;
    int*  cursor  = (int*)p;             p += (size_t)N * 4;
    int*  bsum    = (int*)p;             p += 256 * 4;
    int*  csr_src = (int*)p;             p += (size_t)E * 4;

    const int T  = 256;
    const int nb = cdiv_ll(N, 256);      // <= 256 required by scanB

    // 1) fused setup (also zeroes cnt, inits Aout=bfc2)
    const long long setup_work = (long long)N * 32 + 512 * 128 + 256 * 512
                               + 256 * 128 + (long long)N + (long long)N;
    setup_kernel<<<cdiv_ll(setup_work, T), T, 0, stream>>>(
        emb, W1, W2, Wres, Wfc1, bfc2, embb, W1t, Wct, Wfc1t, cnt, Aout, N);

    // 2) CSR build + dinv (stream order guarantees cnt=0 before hist)
    hist_kernel<<<cdiv_ll(E, T), T, 0, stream>>>(dstv, cnt, E);
    scanA_kernel<<<nb, T, 0, stream>>>(cnt, excl, bsum, N);
    scanB_kernel<<<1, T, 0, stream>>>(bsum, nb);
    scanC_kernel<<<nb, T, 0, stream>>>(excl, bsum, cnt, rowptr, cursor, dinv, N, E);
    fill_kernel<<<cdiv_ll(E, T), T, 0, stream>>>(srcv, dstv, dinv, cursor, csr_src, csr_w, E);

    // 3) aggE = S @ emb  (bf16)
    aggb_kernel<<<cdiv_ll((long long)N * 64, T), T, 0, stream>>>(
        embb, rowptr, csr_src, csr_w, dinv, aggEb, N);

    // 4) x1 = relu(aggE @ W1 + b1) -> bf16 [N,512]   (K=128: no pipe)
    mgemm<1, 0><<<dim3(512 / 256, cdiv_ll(N, 128)), 512, 0, stream>>>(
        aggEb, W1t, N, 512, 128, b1, x1b, nullptr, nullptr);

    // 5) fused: h2 = x1@W2 (bf16), hres = x1@Wres (fp32 -> xout)  (K=512: pipe)
    mgemm<2, 1><<<dim3(1, cdiv_ll(N, 128)), 512, 0, stream>>>(
        x1b, Wct, N, 256, 512, nullptr, h2b, xout, nullptr);

    // 6) fused: x = relu(S@h2 + b2) + hres + bres -> xout (fp32) + xb (bf16)
    aggfin_kernel<<<cdiv_ll((long long)N * 64, T), T, 0, stream>>>(
        h2b, rowptr, csr_src, csr_w, dinv, b2, bres, xout, xb, N);

    // 7) head: A += sum relu(xb@Wfc1t + bfc1) * Wfc2  (A pre-init to bfc2)
    mgemm<3, 0><<<dim3(1, cdiv_ll(N, 128)), 512, 0, stream>>>(
        xb, Wfc1t, N, 256, 128, bfc1, nullptr, Aout, Wfc2);
}